// Round 7
// baseline (741.098 us; speedup 1.0000x reference)
//
#include <hip/hip_runtime.h>
#include <hip/hip_bf16.h>
#include <cstdint>
#include <cstddef>

typedef __bf16 bf16;
typedef __bf16 bf16x8 __attribute__((ext_vector_type(8)));
typedef float f32x4 __attribute__((ext_vector_type(4)));

#define N_PTS 131072
#define CDIM  512
#define C3    1536
#define HD    64
#define NH    8
#define KWIN  128

static __device__ __forceinline__ bf16 cvt(float x) { return (bf16)x; }

// async global->LDS, 16B per lane. LDS dest = wave-uniform base + lane*16.
static __device__ __forceinline__ void gld16(const bf16* g, bf16* l) {
    __builtin_amdgcn_global_load_lds(
        (const __attribute__((address_space(1))) void*)g,
        (__attribute__((address_space(3))) void*)l, 16, 0, 0);
}

// ---------------------------------------------------------------------------
// Weight prep: transpose + cast f32 -> bf16.  Wt[col][k] = W[k][col].
// ---------------------------------------------------------------------------
__global__ __launch_bounds__(256) void k_prep(
    const float* __restrict__ Wqkv, const float* __restrict__ Wproj,
    bf16* __restrict__ Wqkv_t, bf16* __restrict__ Wproj_t)
{
    int idx = blockIdx.x * 256 + threadIdx.x;
    if (idx < CDIM * C3) {
        int k = idx / C3, c = idx % C3;
        Wqkv_t[(size_t)c * CDIM + k] = cvt(Wqkv[idx]);
    } else {
        int j = idx - CDIM * C3;
        if (j < CDIM * CDIM) {
            int k = j / CDIM, c = j % CDIM;
            Wproj_t[(size_t)c * CDIM + k] = cvt(Wproj[j]);
        }
    }
}

// ---------------------------------------------------------------------------
// GEMM v4:  out[m,n] = A[m,:] @ Bt[n,:]^T + bias[n]
// 256x256 tile, BK=32, 8 waves (2M x 4N), wave owns 128x64 (8x4 frags).
//
// B: NEVER in LDS. Wt panels are L2-resident (<=1.5MB); each wave loads its
//    4 B-frags per K-step directly global->reg (16 rows x 64B contiguous per
//    inst), double-buffered one step ahead (bv[2][4], static idx via full
//    unroll). Compiler inserts counted vmcnt before use; zero barriers.
// A: through LDS with the proven rotate-permute layout (R4-R6 conflicts=0):
//    16B slot p of row holds k-slot (p-(row>>1))&3; frag read byte =
//    row*64 + (((g+(row>>1))&3)<<4).
//    - GATHER path (qkv): reg-staged f32 gather: float4 loads issued at step
//      start (latency hides under MFMA), cvt->bf16, ds_write_b64 into the
//      swizzled slots after MFMA; lgkmcnt(0) before the barrier = RAW fence.
//      2-deep ring. Fuses the former k_gather pass.
//    - gld16 path (proj): 3-deep ring, pre-swizzled global source, counted
//      vmcnt(6): in-flight at the wait = A(s+1)[2] (oldest), B(s+1)[4],
//      A(s+2)[2] -> keep 6 newest, retire A(s+1). Never drains mid-loop.
// ONE barrier per K-step: waves skew within the step, so LDS service and
// MFMA overlap across waves (the compiler's counted lgkmcnt handles per-wave
// ds_read->MFMA ordering fine-grained, m97-verified).
// ---------------------------------------------------------------------------
template <bool GATHER, bool F32OUT, int NT>
__global__ __launch_bounds__(512) void k_gemm(
    const void* __restrict__ Ag_, const bf16* __restrict__ Bt,
    const float* __restrict__ bias, const int* __restrict__ order,
    void* __restrict__ outp)
{
    __shared__ __align__(16) bf16 As[3][256 * 32];   // 48 KB ring (2 or 3 used)
    __shared__ int ord_s[256];

    const int t    = threadIdx.x;
    const int lane = t & 63;
    const int wv   = t >> 6;          // 0..7
    const int wr   = wv >> 2;         // 0..1  (M half: 128 rows)
    const int wc   = wv & 3;          // 0..3  (N quarter: 64 cols)
    const int g    = lane >> 4, r16 = lane & 15;

    const int nwg = gridDim.x;
    const int bid = blockIdx.x;
    const int swz = (bid & 7) * (nwg >> 3) + (bid >> 3);  // grids are %8==0
    const int m0  = (swz / NT) * 256;
    const int n0  = (swz % NT) * 256;

    const float* Af = (const float*)Ag_;
    const bf16*  Ab = (const bf16*)Ag_;
    const int NKT = CDIM / 32;   // 16

    if (GATHER) {
        if (t < 256) ord_s[t] = order[m0 + t];
        __syncthreads();
    }

    // ---- GATHER staging map: thread owns chunks c = t + q*512, q=0..3 ----
    // row = c>>3, k4 = c&7 (float4 index within the K32 slice).
    // dst byte = row*64 + (((k4>>1)+(row>>1))&3)*16 + (k4&1)*8  (b64 write)
    size_t gsrc[4]; int gdst[4];
    if (GATHER) {
#pragma unroll
        for (int q = 0; q < 4; ++q) {
            int c = t + q * 512;
            int row = c >> 3, k4 = c & 7;
            gsrc[q] = (size_t)ord_s[row] * CDIM + k4 * 4;
            gdst[q] = row * 64 + ((((k4 >> 1) + (row >> 1)) & 3) << 4) + (k4 & 1) * 8;
        }
    }

    // ---- gld16 staging map (pre-swizzled global source) ----
    const int L0 = wv * 64 + lane;
    const int r0 = L0 >> 2, sl0 = ((L0 & 3) - (r0 >> 1)) & 3;
    const int r1 = r0 + 128, sl1 = ((L0 & 3) - (r1 >> 1)) & 3;
    const bf16* srcA0 = Ab + (size_t)(m0 + r0) * CDIM + sl0 * 8;
    const bf16* srcA1 = Ab + (size_t)(m0 + r1) * CDIM + sl1 * 8;

    // ---- B frag sources (global, L2-hot) ----
    const bf16* srcB[4];
#pragma unroll
    for (int n = 0; n < 4; ++n)
        srcB[n] = Bt + (size_t)(n0 + wc * 64 + n * 16 + r16) * CDIM + g * 8;

    // ---- A frag read offsets (rotate-permuted) ----
    int aoff[8];
#pragma unroll
    for (int i = 0; i < 8; ++i) {
        int row = wr * 128 + i * 16 + r16;
        aoff[i] = row * 64 + (((g + (row >> 1)) & 3) << 4);
    }

    f32x4 acc[8][4];
    const f32x4 z = {0.f, 0.f, 0.f, 0.f};
#pragma unroll
    for (int i = 0; i < 8; ++i)
#pragma unroll
        for (int n = 0; n < 4; ++n) acc[i][n] = z;

    auto stageA_g16 = [&](int s) {       // gld16 path: ring slot s%3
        const int b  = s % 3;
        const int ko = s * 32;
        gld16(srcA0 + ko, &As[b][(size_t)wv * 64 * 8]);
        gld16(srcA1 + ko, &As[b][(size_t)(512 + wv * 64) * 8]);
    };

    bf16x8 bv[2][4];

    // ---------------- prologue ----------------
    if (GATHER) {
        // stage step 0 into buf 0 (f32 latency exposed once)
        float4 f0[4];
#pragma unroll
        for (int q = 0; q < 4; ++q)
            f0[q] = *reinterpret_cast<const float4*>(Af + gsrc[q]);
#pragma unroll
        for (int n = 0; n < 4; ++n)
            bv[0][n] = *reinterpret_cast<const bf16x8*>(srcB[n]);
#pragma unroll
        for (int q = 0; q < 4; ++q) {
            union { bf16 e[4]; uint2 u; } pk;
            pk.e[0] = cvt(f0[q].x); pk.e[1] = cvt(f0[q].y);
            pk.e[2] = cvt(f0[q].z); pk.e[3] = cvt(f0[q].w);
            *reinterpret_cast<uint2*>(
                reinterpret_cast<char*>(&As[0][0]) + gdst[q]) = pk.u;
        }
        asm volatile("s_waitcnt lgkmcnt(0)" ::: "memory");
        __builtin_amdgcn_s_barrier();
    } else {
        stageA_g16(0); stageA_g16(1);
#pragma unroll
        for (int n = 0; n < 4; ++n)
            bv[0][n] = *reinterpret_cast<const bf16x8*>(srcB[n]);
        // in flight: A0(2) oldest, A1(2), B0(4) -> retire A0
        asm volatile("s_waitcnt vmcnt(6)" ::: "memory");
        __builtin_amdgcn_s_barrier();
    }

    // ---------------- main loop (fully unrolled; bv indices static) --------
#pragma unroll
    for (int s = 0; s < NKT; ++s) {
        const int rb = GATHER ? (s & 1) : (s % 3);
        const char* abase = reinterpret_cast<const char*>(&As[rb][0]);

        // issue next-step loads first (oldest = f32/A, then B)
        float4 fA[4];
        if (GATHER && s < NKT - 1) {
#pragma unroll
            for (int q = 0; q < 4; ++q)
                fA[q] = *reinterpret_cast<const float4*>(
                    Af + gsrc[q] + (size_t)(s + 1) * 32);
        }
        if (!GATHER && s < NKT - 2) stageA_g16(s + 2);
        if (s < NKT - 1) {
#pragma unroll
            for (int n = 0; n < 4; ++n)
                bv[(s + 1) & 1][n] = *reinterpret_cast<const bf16x8*>(
                    srcB[n] + (s + 1) * 32);
        }

        // A frags from LDS (compiler-counted lgkm under the MFMAs)
        bf16x8 af[8];
#pragma unroll
        for (int i = 0; i < 8; ++i)
            af[i] = *reinterpret_cast<const bf16x8*>(abase + aoff[i]);

        __builtin_amdgcn_s_setprio(1);
#pragma unroll
        for (int i = 0; i < 8; ++i)
#pragma unroll
            for (int n = 0; n < 4; ++n)
                acc[i][n] = __builtin_amdgcn_mfma_f32_16x16x32_bf16(
                    af[i], bv[s & 1][n], acc[i][n], 0, 0, 0);
        __builtin_amdgcn_s_setprio(0);

        if (GATHER) {
            if (s < NKT - 1) {
                const int wb = (s + 1) & 1;
#pragma unroll
                for (int q = 0; q < 4; ++q) {
                    union { bf16 e[4]; uint2 u; } pk;
                    pk.e[0] = cvt(fA[q].x); pk.e[1] = cvt(fA[q].y);
                    pk.e[2] = cvt(fA[q].z); pk.e[3] = cvt(fA[q].w);
                    *reinterpret_cast<uint2*>(
                        reinterpret_cast<char*>(&As[wb][0]) + gdst[q]) = pk.u;
                }
                asm volatile("s_waitcnt lgkmcnt(0)" ::: "memory");
                __builtin_amdgcn_s_barrier();
            }
        } else {
            if (s < NKT - 2) {
                // in flight: A(s+1)[2] oldest, B(s+1)[4], A(s+2)[2]
                asm volatile("s_waitcnt vmcnt(6)" ::: "memory");
                __builtin_amdgcn_s_barrier();
            } else if (s == NKT - 2) {
                // in flight: A(s+1)[2] oldest, B(s+1)[4]
                asm volatile("s_waitcnt vmcnt(4)" ::: "memory");
                __builtin_amdgcn_s_barrier();
            }
        }
    }

    // ---------------- epilogue: D layout col=lane&15, row=(lane>>4)*4+j ----
    const int ldo = NT * 256;
#pragma unroll
    for (int n = 0; n < 4; ++n) {
        int col = n0 + wc * 64 + n * 16 + r16;
        float b = bias[col];
#pragma unroll
        for (int i = 0; i < 8; ++i)
#pragma unroll
            for (int j = 0; j < 4; ++j) {
                int row = m0 + wr * 128 + i * 16 + g * 4 + j;
                if (F32OUT)
                    reinterpret_cast<float*>(outp)[(size_t)row * ldo + col] =
                        acc[i][n][j] + b;
                else
                    reinterpret_cast<bf16*>(outp)[(size_t)row * ldo + col] =
                        cvt(acc[i][n][j] + b);
            }
    }
}

// ---------------------------------------------------------------------------
// Attention: one block per (window, head). 4 waves, each owns 32 query rows.
// Output rows are SCATTERED to attn_g[order[w*128+tok]] so that k_proj's A
// operand is sequential (order[inverse[n]] == n).
// ---------------------------------------------------------------------------
__global__ __launch_bounds__(256) void k_attn(
    const bf16* __restrict__ qkv_s, const int* __restrict__ order,
    bf16* __restrict__ attn_g)
{
    __shared__ __align__(16) char smem[36864 + 64 * 136 * 2];
    __shared__ int ord_s[KWIN];
    bf16 (*Q)[72]   = reinterpret_cast<bf16 (*)[72]>(smem);
    bf16 (*Kt)[72]  = reinterpret_cast<bf16 (*)[72]>(smem + 128 * 72 * 2);
    bf16 (*P)[136]  = reinterpret_cast<bf16 (*)[136]>(smem);          // overlaps Q,K
    bf16 (*Vt)[136] = reinterpret_cast<bf16 (*)[136]>(smem + 36864);  // V transposed

    const int t    = threadIdx.x;
    const int lane = t & 63;
    const int wv   = t >> 6;
    const int g    = lane >> 4, r16 = lane & 15;
    const int h    = blockIdx.x;
    const int w    = blockIdx.y;

    const bf16* base = qkv_s + (size_t)w * KWIN * C3 + h * HD;

    if (t < KWIN) ord_s[t] = order[w * KWIN + t];

    // stage Q, K (row-major [tok][d]) and V transposed [d][tok]
#pragma unroll
    for (int it = 0; it < 4; ++it) {
        int s   = it * 256 + t;      // 0..1023
        int tok = s >> 3;
        int c8  = (s & 7) << 3;
        size_t roff = (size_t)tok * C3 + c8;
        *reinterpret_cast<uint4*>(&Q[tok][c8])  =
            *reinterpret_cast<const uint4*>(base + roff);
        *reinterpret_cast<uint4*>(&Kt[tok][c8]) =
            *reinterpret_cast<const uint4*>(base + roff + CDIM);
        uint4 vvec = *reinterpret_cast<const uint4*>(base + roff + 2 * CDIM);
        const bf16* ve = reinterpret_cast<const bf16*>(&vvec);
#pragma unroll
        for (int i = 0; i < 8; ++i) Vt[c8 + i][tok] = ve[i];
    }
    __syncthreads();

    // S = Q K^T for rows [wv*32, wv*32+32)
    f32x4 sc[2][8];
    const f32x4 z = {0.f, 0.f, 0.f, 0.f};
#pragma unroll
    for (int m = 0; m < 2; ++m)
#pragma unroll
        for (int n = 0; n < 8; ++n) sc[m][n] = z;

#pragma unroll
    for (int ks = 0; ks < 2; ++ks) {
        bf16x8 aq[2];
#pragma unroll
        for (int m = 0; m < 2; ++m)
            aq[m] = *reinterpret_cast<const bf16x8*>(
                &Q[wv * 32 + m * 16 + r16][ks * 32 + g * 8]);
#pragma unroll
        for (int n = 0; n < 8; ++n) {
            bf16x8 bk = *reinterpret_cast<const bf16x8*>(
                &Kt[n * 16 + r16][ks * 32 + g * 8]);
#pragma unroll
            for (int m = 0; m < 2; ++m)
                sc[m][n] = __builtin_amdgcn_mfma_f32_16x16x32_bf16(
                    aq[m], bk, sc[m][n], 0, 0, 0);
        }
    }

    // softmax (f32), row-parallel over 16-lane groups
    const float scale = 0.125f;   // hd^-0.5
    float inv_sum[2][4];
#pragma unroll
    for (int m = 0; m < 2; ++m) {
#pragma unroll
        for (int j = 0; j < 4; ++j) {
            float mx = -3.0e38f;
#pragma unroll
            for (int n = 0; n < 8; ++n) mx = fmaxf(mx, sc[m][n][j]);
            mx = fmaxf(mx, __shfl_xor(mx, 1));
            mx = fmaxf(mx, __shfl_xor(mx, 2));
            mx = fmaxf(mx, __shfl_xor(mx, 4));
            mx = fmaxf(mx, __shfl_xor(mx, 8));
            mx *= scale;
            float ssum = 0.f;
#pragma unroll
            for (int n = 0; n < 8; ++n) {
                float p = __expf(sc[m][n][j] * scale - mx);
                sc[m][n][j] = p;
                ssum += p;
            }
            ssum += __shfl_xor(ssum, 1);
            ssum += __shfl_xor(ssum, 2);
            ssum += __shfl_xor(ssum, 4);
            ssum += __shfl_xor(ssum, 8);
            inv_sum[m][j] = 1.f / ssum;
        }
    }

    __syncthreads();   // all waves done reading Q/Kt before P overwrites them

    // write normalized P (bf16)
#pragma unroll
    for (int m = 0; m < 2; ++m)
#pragma unroll
        for (int n = 0; n < 8; ++n)
#pragma unroll
            for (int j = 0; j < 4; ++j)
                P[wv * 32 + m * 16 + g * 4 + j][n * 16 + r16] =
                    cvt(sc[m][n][j] * inv_sum[m][j]);

    // O = P V   (32x64 per wave)
    f32x4 o[2][4];
#pragma unroll
    for (int m = 0; m < 2; ++m)
#pragma unroll
        for (int n = 0; n < 4; ++n) o[m][n] = z;

#pragma unroll
    for (int kt = 0; kt < 4; ++kt) {
        bf16x8 ap[2];
#pragma unroll
        for (int m = 0; m < 2; ++m)
            ap[m] = *reinterpret_cast<const bf16x8*>(
                &P[wv * 32 + m * 16 + r16][kt * 32 + g * 8]);
#pragma unroll
        for (int n = 0; n < 4; ++n) {
            bf16x8 bvv = *reinterpret_cast<const bf16x8*>(
                &Vt[n * 16 + r16][kt * 32 + g * 8]);
#pragma unroll
            for (int m = 0; m < 2; ++m)
                o[m][n] = __builtin_amdgcn_mfma_f32_16x16x32_bf16(
                    ap[m], bvv, o[m][n], 0, 0, 0);
        }
    }

    // scatter rows to unserialized position: attn_g[order[i]] = ser[i]
#pragma unroll
    for (int m = 0; m < 2; ++m)
#pragma unroll
        for (int n = 0; n < 4; ++n)
#pragma unroll
            for (int j = 0; j < 4; ++j) {
                int tok  = wv * 32 + m * 16 + g * 4 + j;
                int d    = n * 16 + r16;
                int drow = ord_s[tok];
                attn_g[(size_t)drow * CDIM + h * HD + d] = cvt(o[m][n][j]);
            }
}

// ---------------------------------------------------------------------------
extern "C" void kernel_launch(void* const* d_in, const int* in_sizes, int n_in,
                              void* d_out, int out_size, void* d_ws, size_t ws_size,
                              hipStream_t stream)
{
    const float* feat    = (const float*)d_in[0];
    const float* Wqkv    = (const float*)d_in[1];
    const float* bqkv    = (const float*)d_in[2];
    const float* Wproj   = (const float*)d_in[3];
    const float* bproj   = (const float*)d_in[4];
    const int*   order   = (const int*)d_in[5];
    float* out = (float*)d_out;

    const size_t qkv_bytes  = (size_t)N_PTS * C3 * sizeof(bf16);    // 402.7 MB
    const size_t gat_bytes  = (size_t)N_PTS * CDIM * sizeof(bf16);  // 134.2 MB (attn_g)
    const size_t wq_bytes   = (size_t)C3 * CDIM * sizeof(bf16);
    const size_t wp_bytes   = (size_t)CDIM * CDIM * sizeof(bf16);
    if (ws_size < qkv_bytes + gat_bytes + wq_bytes + wp_bytes) return;

    bf16* qkv_s   = (bf16*)d_ws;
    bf16* attn_g  = (bf16*)((char*)d_ws + qkv_bytes);
    bf16* Wqkv_t  = (bf16*)((char*)d_ws + qkv_bytes + gat_bytes);
    bf16* Wproj_t = (bf16*)((char*)d_ws + qkv_bytes + gat_bytes + wq_bytes);

    k_prep<<<dim3((CDIM * C3 + CDIM * CDIM + 255) / 256), 256, 0, stream>>>(
        Wqkv, Wproj, Wqkv_t, Wproj_t);
    // qkv GEMM with fused gather: [131072 x 1536] = bf16(feat[order]) @ Wqkv_t^T
    k_gemm<true, false, C3 / 256>
        <<<dim3((N_PTS / 256) * (C3 / 256)), 512, 0, stream>>>(
        feat, Wqkv_t, bqkv, order, qkv_s);
    // attention (reads qkv_s, scatters into attn_g)
    k_attn<<<dim3(NH, N_PTS / KWIN), 256, 0, stream>>>(qkv_s, order, attn_g);
    // proj GEMM: [131072 x 512] = attn_g @ Wproj_t^T  (f32 out)
    k_gemm<false, true, CDIM / 256>
        <<<dim3((N_PTS / 256) * (CDIM / 256)), 512, 0, stream>>>(
        attn_g, Wproj_t, bproj, order, out);
}

// Round 8
// 597.996 us; speedup vs baseline: 1.2393x; 1.2393x over previous
//
#include <hip/hip_runtime.h>
#include <hip/hip_bf16.h>
#include <cstdint>
#include <cstddef>

typedef __bf16 bf16;
typedef __bf16 bf16x8 __attribute__((ext_vector_type(8)));
typedef float f32x4 __attribute__((ext_vector_type(4)));

#define N_PTS 131072
#define CDIM  512
#define C3    1536
#define HD    64
#define NH    8
#define KWIN  128

static __device__ __forceinline__ bf16 cvt(float x) { return (bf16)x; }

// async global->LDS, 16B per lane. LDS dest = wave-uniform base + lane*16.
static __device__ __forceinline__ void gld16(const bf16* g, bf16* l) {
    __builtin_amdgcn_global_load_lds(
        (const __attribute__((address_space(1))) void*)g,
        (__attribute__((address_space(3))) void*)l, 16, 0, 0);
}

// ---------------------------------------------------------------------------
// Weight prep: transpose + cast f32 -> bf16.  Wt[col][k] = W[k][col].
// ---------------------------------------------------------------------------
__global__ __launch_bounds__(256) void k_prep(
    const float* __restrict__ Wqkv, const float* __restrict__ Wproj,
    bf16* __restrict__ Wqkv_t, bf16* __restrict__ Wproj_t)
{
    int idx = blockIdx.x * 256 + threadIdx.x;
    if (idx < CDIM * C3) {
        int k = idx / C3, c = idx % C3;
        Wqkv_t[(size_t)c * CDIM + k] = cvt(Wqkv[idx]);
    } else {
        int j = idx - CDIM * C3;
        if (j < CDIM * CDIM) {
            int k = j / CDIM, c = j % CDIM;
            Wproj_t[(size_t)c * CDIM + k] = cvt(Wproj[j]);
        }
    }
}

// ---------------------------------------------------------------------------
// GEMM (R5 structure, proven 292us / conflicts=0), + fused gather on A:
//   out[m,n] = A[m,:] @ Bt[n,:]^T + bias[n]
// 128x256 tile, BK=32, 8 waves (2M x 4N), wave owns 64x64 (acc 64 AGPR ->
// 128 unified regs -> 2 blocks/CU). 2-deep LDS ring: (A 8KB + B 16KB) x 2.
//
// B (both paths): gld16 into LDS, pre-swizzled global source (rotate-permute:
//   16B slot p of row holds k-slot (p-(row>>1))&3; reader byte =
//   row*64 + (((g+(row>>1))&3)<<4)) — verified conflict-free R4-R6.
// A:
//  GATHER=false (proj): gld16, same as B.
//  GATHER=true (qkv):   reg-staged fused gather: thread owns chunk t
//   (row=t>>2, k-slot ks=(t&3-(row>>1))&3); loads 2x float4 from
//   feat[ord_s[row]][s*32 + ks*8 ..] issued ONE STEP EARLY (latency hides
//   under compute), cvt->bf16x8, one ds_write_b128 at byte t*16 — identical
//   chunk/permutation as gld16 would produce, so reader offsets unchanged.
//   The pack's implicit vmcnt wait (f32 regs) drains all older loads incl.
//   B(s+1), so no manual vmcnt needed except the tail.
// ---------------------------------------------------------------------------
template <bool GATHER, bool F32OUT, int NT>
__global__ __launch_bounds__(512, 4) void k_gemm(
    const void* __restrict__ Ag_, const bf16* __restrict__ Bt,
    const float* __restrict__ bias, const int* __restrict__ order,
    void* __restrict__ outp)
{
    __shared__ __align__(16) bf16 As[2][128 * 32];   // 16 KB
    __shared__ __align__(16) bf16 Bs[2][256 * 32];   // 32 KB
    __shared__ int ord_s[128];

    const int t    = threadIdx.x;
    const int lane = t & 63;
    const int wv   = t >> 6;          // 0..7
    const int wr   = wv >> 2;         // 0..1  (M half: 64 rows)
    const int wc   = wv & 3;          // 0..3  (N quarter: 64 cols)
    const int g    = lane >> 4, r16 = lane & 15;

    const int nwg = gridDim.x;
    const int bid = blockIdx.x;
    const int swz = (bid & 7) * (nwg >> 3) + (bid >> 3);  // grids are %8==0
    const int m0  = (swz / NT) * 128;
    const int n0  = (swz % NT) * 256;

    const float* Af = (const float*)Ag_;
    const bf16*  Ab = (const bf16*)Ag_;
    const int NKT = CDIM / 32;   // 16

    if (GATHER) {
        if (t < 128) ord_s[t] = order[m0 + t];
        __syncthreads();
    }

    // ---- A chunk ownership (chunk t of 512): row, phys slot, src k-slot ----
    const int rowA = t >> 2;
    const int ksA  = ((t & 3) - (rowA >> 1)) & 3;
    const float* gsrcA = GATHER
        ? Af + (size_t)ord_s[rowA] * CDIM + ksA * 8 : nullptr;
    const bf16* srcA_l = Ab + (size_t)(m0 + rowA) * CDIM + ksA * 8;

    // ---- B staging: chunks t and t+512 (rows 0..127 / 128..255) ----
    const int rB0 = t >> 2,        sB0 = ((t & 3) - (rB0 >> 1)) & 3;
    const int rB1 = rB0 + 128,     sB1 = ((t & 3) - (rB1 >> 1)) & 3;
    const bf16* srcB0 = Bt + (size_t)(n0 + rB0) * CDIM + sB0 * 8;
    const bf16* srcB1 = Bt + (size_t)(n0 + rB1) * CDIM + sB1 * 8;

    // ---- fragment read byte-offsets (rotate-permuted slots) ----
    int aoff[4], boff[4];
#pragma unroll
    for (int m = 0; m < 4; ++m) {
        int row = wr * 64 + m * 16 + r16;
        aoff[m] = row * 64 + (((g + (row >> 1)) & 3) << 4);
    }
#pragma unroll
    for (int n = 0; n < 4; ++n) {
        int row = wc * 64 + n * 16 + r16;
        boff[n] = row * 64 + (((g + (row >> 1)) & 3) << 4);
    }

    f32x4 acc[4][4];
    const f32x4 z = {0.f, 0.f, 0.f, 0.f};
#pragma unroll
    for (int m = 0; m < 4; ++m)
#pragma unroll
        for (int n = 0; n < 4; ++n) acc[m][n] = z;

    auto stageB = [&](int s) {
        const int b = s & 1;
        gld16(srcB0 + s * 32, &Bs[b][(size_t)wv * 64 * 8]);
        gld16(srcB1 + s * 32, &Bs[b][(size_t)(512 + wv * 64) * 8]);
    };
    auto stageA_l = [&](int s) {
        const int b = s & 1;
        gld16(srcA_l + s * 32, &As[b][(size_t)wv * 64 * 8]);
    };
    auto packA = [&](int s, float4 fa, float4 fb) {
        union { bf16 e[8]; uint4 u; } pk;
        pk.e[0] = cvt(fa.x); pk.e[1] = cvt(fa.y);
        pk.e[2] = cvt(fa.z); pk.e[3] = cvt(fa.w);
        pk.e[4] = cvt(fb.x); pk.e[5] = cvt(fb.y);
        pk.e[6] = cvt(fb.z); pk.e[7] = cvt(fb.w);
        *reinterpret_cast<uint4*>(
            reinterpret_cast<char*>(&As[s & 1][0]) + t * 16) = pk.u;
    };
    auto compute = [&](int s) {
        const int b = s & 1;
        const char* ab = reinterpret_cast<const char*>(&As[b][0]);
        const char* bb = reinterpret_cast<const char*>(&Bs[b][0]);
        bf16x8 af[4], bvv[4];
#pragma unroll
        for (int m = 0; m < 4; ++m)
            af[m] = *reinterpret_cast<const bf16x8*>(ab + aoff[m]);
#pragma unroll
        for (int n = 0; n < 4; ++n)
            bvv[n] = *reinterpret_cast<const bf16x8*>(bb + boff[n]);
        __builtin_amdgcn_s_setprio(1);
#pragma unroll
        for (int m = 0; m < 4; ++m)
#pragma unroll
            for (int n = 0; n < 4; ++n)
                acc[m][n] = __builtin_amdgcn_mfma_f32_16x16x32_bf16(
                    af[m], bvv[n], acc[m][n], 0, 0, 0);
        __builtin_amdgcn_s_setprio(0);
    };

    // ---------------- prologue ----------------
    if (GATHER) {
        float4 fa0 = *reinterpret_cast<const float4*>(gsrcA);
        float4 fb0 = *reinterpret_cast<const float4*>(gsrcA + 4);
        float4 fa1 = *reinterpret_cast<const float4*>(gsrcA + 32);
        float4 fb1 = *reinterpret_cast<const float4*>(gsrcA + 36);
        stageB(0); stageB(1);
        packA(0, fa0, fb0);
        packA(1, fa1, fb1);
        // packs' implicit waits drained the f32s; B(0),B(1) outstanding.
        asm volatile("s_waitcnt vmcnt(2) lgkmcnt(0)" ::: "memory");
        __builtin_amdgcn_s_barrier();
    } else {
        stageA_l(0); stageB(0);
        stageA_l(1); stageB(1);
        // outstanding: tile0(3) oldest, tile1(3) -> retire tile0
        asm volatile("s_waitcnt vmcnt(3)" ::: "memory");
        __builtin_amdgcn_s_barrier();
    }

    // ---------------- main loop ----------------
#pragma unroll
    for (int s = 0; s < NKT; ++s) {
        float4 fa, fb;
        if (GATHER && s + 2 < NKT) {
            fa = *reinterpret_cast<const float4*>(gsrcA + (s + 2) * 32);
            fb = *reinterpret_cast<const float4*>(gsrcA + (s + 2) * 32 + 4);
        }
        compute(s);
        if (s == NKT - 1) break;
        asm volatile("s_waitcnt lgkmcnt(0)" ::: "memory");
        __builtin_amdgcn_s_barrier();           // all waves done reading buf[s&1]
        if (GATHER) {
            if (s + 2 < NKT) {
                packA(s + 2, fa, fb);           // implicit vmcnt wait drains <= B(s+1)
                stageB(s + 2);
                asm volatile("s_waitcnt lgkmcnt(0)" ::: "memory");
            } else {  // s == NKT-2: B(NKT-1) still outstanding
                asm volatile("s_waitcnt vmcnt(0)" ::: "memory");
            }
        } else {
            if (s + 2 < NKT) {
                stageA_l(s + 2); stageB(s + 2);
                // outstanding: tile s+1 (3) oldest, tile s+2 (3)
                asm volatile("s_waitcnt vmcnt(3)" ::: "memory");
            } else {
                asm volatile("s_waitcnt vmcnt(0)" ::: "memory");
            }
        }
        __builtin_amdgcn_s_barrier();
    }

    // ---------------- epilogue: D layout col=lane&15, row=(lane>>4)*4+j ----
    const int ldo = NT * 256;
#pragma unroll
    for (int n = 0; n < 4; ++n) {
        int col = n0 + wc * 64 + n * 16 + r16;
        float b = bias[col];
#pragma unroll
        for (int m = 0; m < 4; ++m)
#pragma unroll
            for (int j = 0; j < 4; ++j) {
                int row = m0 + wr * 64 + m * 16 + g * 4 + j;
                if (F32OUT)
                    reinterpret_cast<float*>(outp)[(size_t)row * ldo + col] =
                        acc[m][n][j] + b;
                else
                    reinterpret_cast<bf16*>(outp)[(size_t)row * ldo + col] =
                        cvt(acc[m][n][j] + b);
            }
    }
}

// ---------------------------------------------------------------------------
// Attention: one block per (window, head). 4 waves, each owns 32 query rows.
// Output rows are SCATTERED to attn_g[order[w*128+tok]] so that k_proj's A
// operand is sequential (order[inverse[n]] == n).
// ---------------------------------------------------------------------------
__global__ __launch_bounds__(256) void k_attn(
    const bf16* __restrict__ qkv_s, const int* __restrict__ order,
    bf16* __restrict__ attn_g)
{
    __shared__ __align__(16) char smem[36864 + 64 * 136 * 2];
    __shared__ int ord_s[KWIN];
    bf16 (*Q)[72]   = reinterpret_cast<bf16 (*)[72]>(smem);
    bf16 (*Kt)[72]  = reinterpret_cast<bf16 (*)[72]>(smem + 128 * 72 * 2);
    bf16 (*P)[136]  = reinterpret_cast<bf16 (*)[136]>(smem);          // overlaps Q,K
    bf16 (*Vt)[136] = reinterpret_cast<bf16 (*)[136]>(smem + 36864);  // V transposed

    const int t    = threadIdx.x;
    const int lane = t & 63;
    const int wv   = t >> 6;
    const int g    = lane >> 4, r16 = lane & 15;
    const int h    = blockIdx.x;
    const int w    = blockIdx.y;

    const bf16* base = qkv_s + (size_t)w * KWIN * C3 + h * HD;

    if (t < KWIN) ord_s[t] = order[w * KWIN + t];

    // stage Q, K (row-major [tok][d]) and V transposed [d][tok]
#pragma unroll
    for (int it = 0; it < 4; ++it) {
        int s   = it * 256 + t;      // 0..1023
        int tok = s >> 3;
        int c8  = (s & 7) << 3;
        size_t roff = (size_t)tok * C3 + c8;
        *reinterpret_cast<uint4*>(&Q[tok][c8])  =
            *reinterpret_cast<const uint4*>(base + roff);
        *reinterpret_cast<uint4*>(&Kt[tok][c8]) =
            *reinterpret_cast<const uint4*>(base + roff + CDIM);
        uint4 vvec = *reinterpret_cast<const uint4*>(base + roff + 2 * CDIM);
        const bf16* ve = reinterpret_cast<const bf16*>(&vvec);
#pragma unroll
        for (int i = 0; i < 8; ++i) Vt[c8 + i][tok] = ve[i];
    }
    __syncthreads();

    // S = Q K^T for rows [wv*32, wv*32+32)
    f32x4 sc[2][8];
    const f32x4 z = {0.f, 0.f, 0.f, 0.f};
#pragma unroll
    for (int m = 0; m < 2; ++m)
#pragma unroll
        for (int n = 0; n < 8; ++n) sc[m][n] = z;

#pragma unroll
    for (int ks = 0; ks < 2; ++ks) {
        bf16x8 aq[2];
#pragma unroll
        for (int m = 0; m < 2; ++m)
            aq[m] = *reinterpret_cast<const bf16x8*>(
                &Q[wv * 32 + m * 16 + r16][ks * 32 + g * 8]);
#pragma unroll
        for (int n = 0; n < 8; ++n) {
            bf16x8 bk = *reinterpret_cast<const bf16x8*>(
                &Kt[n * 16 + r16][ks * 32 + g * 8]);
#pragma unroll
            for (int m = 0; m < 2; ++m)
                sc[m][n] = __builtin_amdgcn_mfma_f32_16x16x32_bf16(
                    aq[m], bk, sc[m][n], 0, 0, 0);
        }
    }

    // softmax (f32), row-parallel over 16-lane groups
    const float scale = 0.125f;   // hd^-0.5
    float inv_sum[2][4];
#pragma unroll
    for (int m = 0; m < 2; ++m) {
#pragma unroll
        for (int j = 0; j < 4; ++j) {
            float mx = -3.0e38f;
#pragma unroll
            for (int n = 0; n < 8; ++n) mx = fmaxf(mx, sc[m][n][j]);
            mx = fmaxf(mx, __shfl_xor(mx, 1));
            mx = fmaxf(mx, __shfl_xor(mx, 2));
            mx = fmaxf(mx, __shfl_xor(mx, 4));
            mx = fmaxf(mx, __shfl_xor(mx, 8));
            mx *= scale;
            float ssum = 0.f;
#pragma unroll
            for (int n = 0; n < 8; ++n) {
                float p = __expf(sc[m][n][j] * scale - mx);
                sc[m][n][j] = p;
                ssum += p;
            }
            ssum += __shfl_xor(ssum, 1);
            ssum += __shfl_xor(ssum, 2);
            ssum += __shfl_xor(ssum, 4);
            ssum += __shfl_xor(ssum, 8);
            inv_sum[m][j] = 1.f / ssum;
        }
    }

    __syncthreads();   // all waves done reading Q/Kt before P overwrites them

    // write normalized P (bf16)
#pragma unroll
    for (int m = 0; m < 2; ++m)
#pragma unroll
        for (int n = 0; n < 8; ++n)
#pragma unroll
            for (int j = 0; j < 4; ++j)
                P[wv * 32 + m * 16 + g * 4 + j][n * 16 + r16] =
                    cvt(sc[m][n][j] * inv_sum[m][j]);

    // O = P V   (32x64 per wave)
    f32x4 o[2][4];
#pragma unroll
    for (int m = 0; m < 2; ++m)
#pragma unroll
        for (int n = 0; n < 4; ++n) o[m][n] = z;

#pragma unroll
    for (int kt = 0; kt < 4; ++kt) {
        bf16x8 ap[2];
#pragma unroll
        for (int m = 0; m < 2; ++m)
            ap[m] = *reinterpret_cast<const bf16x8*>(
                &P[wv * 32 + m * 16 + r16][kt * 32 + g * 8]);
#pragma unroll
        for (int n = 0; n < 4; ++n) {
            bf16x8 bvv = *reinterpret_cast<const bf16x8*>(
                &Vt[n * 16 + r16][kt * 32 + g * 8]);
#pragma unroll
            for (int m = 0; m < 2; ++m)
                o[m][n] = __builtin_amdgcn_mfma_f32_16x16x32_bf16(
                    ap[m], bvv, o[m][n], 0, 0, 0);
        }
    }

    // scatter rows to unserialized position: attn_g[order[i]] = ser[i]
#pragma unroll
    for (int m = 0; m < 2; ++m)
#pragma unroll
        for (int n = 0; n < 4; ++n)
#pragma unroll
            for (int j = 0; j < 4; ++j) {
                int tok  = wv * 32 + m * 16 + g * 4 + j;
                int d    = n * 16 + r16;
                int drow = ord_s[tok];
                attn_g[(size_t)drow * CDIM + h * HD + d] = cvt(o[m][n][j]);
            }
}

// ---------------------------------------------------------------------------
extern "C" void kernel_launch(void* const* d_in, const int* in_sizes, int n_in,
                              void* d_out, int out_size, void* d_ws, size_t ws_size,
                              hipStream_t stream)
{
    const float* feat    = (const float*)d_in[0];
    const float* Wqkv    = (const float*)d_in[1];
    const float* bqkv    = (const float*)d_in[2];
    const float* Wproj   = (const float*)d_in[3];
    const float* bproj   = (const float*)d_in[4];
    const int*   order   = (const int*)d_in[5];
    float* out = (float*)d_out;

    const size_t qkv_bytes  = (size_t)N_PTS * C3 * sizeof(bf16);    // 402.7 MB
    const size_t gat_bytes  = (size_t)N_PTS * CDIM * sizeof(bf16);  // 134.2 MB (attn_g)
    const size_t wq_bytes   = (size_t)C3 * CDIM * sizeof(bf16);
    const size_t wp_bytes   = (size_t)CDIM * CDIM * sizeof(bf16);
    if (ws_size < qkv_bytes + gat_bytes + wq_bytes + wp_bytes) return;

    bf16* qkv_s   = (bf16*)d_ws;
    bf16* attn_g  = (bf16*)((char*)d_ws + qkv_bytes);
    bf16* Wqkv_t  = (bf16*)((char*)d_ws + qkv_bytes + gat_bytes);
    bf16* Wproj_t = (bf16*)((char*)d_ws + qkv_bytes + gat_bytes + wq_bytes);

    k_prep<<<dim3((CDIM * C3 + CDIM * CDIM + 255) / 256), 256, 0, stream>>>(
        Wqkv, Wproj, Wqkv_t, Wproj_t);
    // qkv GEMM with fused gather: [131072 x 1536] = bf16(feat[order]) @ Wqkv_t^T
    k_gemm<true, false, C3 / 256>
        <<<dim3((N_PTS / 128) * (C3 / 256)), 512, 0, stream>>>(
        feat, Wqkv_t, bqkv, order, qkv_s);
    // attention (reads qkv_s, scatters into attn_g)
    k_attn<<<dim3(NH, N_PTS / KWIN), 256, 0, stream>>>(qkv_s, order, attn_g);
    // proj GEMM: [131072 x 512] = attn_g @ Wproj_t^T  (f32 out)
    k_gemm<false, true, CDIM / 256>
        <<<dim3((N_PTS / 128) * (CDIM / 256)), 512, 0, stream>>>(
        attn_g, Wproj_t, bproj, order, out);
}